// Round 15
// baseline (165.099 us; speedup 1.0000x reference)
//
#include <hip/hip_runtime.h>
#include <hip/hip_bf16.h>

typedef __bf16 bf16_t;
typedef __bf16 bf16x8 __attribute__((ext_vector_type(8)));
typedef __bf16 bf16x4 __attribute__((ext_vector_type(4)));
typedef float f32x4 __attribute__((ext_vector_type(4)));

#define HD 128
#define NN 384
#define ROWS 768           // B*N
#define SZ 98304           // ROWS*HD
#define JC 3               // j-chunks per (b,i): block covers 128 j, wave covers 32 j (2 tiles)
// ws f32 layout: [0..4*SZ) = AhC, Bh, Vh, Uh ; [4*SZ..7*SZ) = wagg [JC][ROWS][HD];
// flag at ws[7*SZ]

// ---- runtime input-dtype detector: 1 if buffer holds f32, 0 if bf16 ----
__device__ inline int detect_f32(const void* p) {
    const unsigned short* u = (const unsigned short*)p;
    int bad = 0;
    #pragma unroll
    for (int k = 0; k < 128; ++k) {
        int e = (u[k] >> 7) & 0xFF;
        bad += (e < 110 || e > 135) ? 1 : 0;
    }
    return bad >= 16 ? 1 : 0;
}

__global__ __launch_bounds__(64) void detect_kernel(const void* p, float* ws) {
    if (threadIdx.x == 0)
        *(int*)((char*)ws + (size_t)7 * SZ * 4) = detect_f32(p);
}

__device__ inline int read_flag(const float* ws) {
    return *(const int*)((const char*)ws + (size_t)7 * SZ * 4);
}

// ---- DPP 16-lane (row) sum reduction: quad_perm ^1, ^2 then row_ror 4, 8 ----
template<int CTRL>
__device__ __attribute__((always_inline)) inline float dpp_add(float x) {
    int xi = __builtin_bit_cast(int, x);
    int yi = __builtin_amdgcn_update_dpp(0, xi, CTRL, 0xF, 0xF, true);
    return x + __builtin_bit_cast(float, yi);
}
__device__ __attribute__((always_inline)) inline float row16_sum(float x) {
    x = dpp_add<0xB1>(x);    // quad_perm(1,0,3,2): ^1
    x = dpp_add<0x4E>(x);    // quad_perm(2,3,0,1): ^2
    x = dpp_add<0x124>(x);   // row_ror:4
    x = dpp_add<0x128>(x);   // row_ror:8
    return x;
}

// ---- dtype-generic load helpers ----
__device__ __attribute__((always_inline)) inline void ld8(const float* p, float* o) {
    f32x4 a = *(const f32x4*)p;
    f32x4 b = *(const f32x4*)(p + 4);
    o[0] = a[0]; o[1] = a[1]; o[2] = a[2]; o[3] = a[3];
    o[4] = b[0]; o[5] = b[1]; o[6] = b[2]; o[7] = b[3];
}
__device__ __attribute__((always_inline)) inline void ld8(const bf16_t* p, float* o) {
    bf16x8 v = *(const bf16x8*)p;
    #pragma unroll
    for (int e = 0; e < 8; ++e) o[e] = (float)v[e];
}
__device__ __attribute__((always_inline)) inline bf16x8 ld8b(const float* p) {
    f32x4 a = *(const f32x4*)p;
    f32x4 b = *(const f32x4*)(p + 4);
    bf16x8 v;
    #pragma unroll
    for (int e = 0; e < 4; ++e) { v[e] = (bf16_t)a[e]; v[e + 4] = (bf16_t)b[e]; }
    return v;
}
__device__ __attribute__((always_inline)) inline bf16x8 ld8b(const bf16_t* p) { return *(const bf16x8*)p; }
__device__ __attribute__((always_inline)) inline bf16x4 ld4b(const float* p) {
    f32x4 a = *(const f32x4*)p;
    bf16x4 v;
    #pragma unroll
    for (int e = 0; e < 4; ++e) v[e] = (bf16_t)a[e];
    return v;
}
__device__ __attribute__((always_inline)) inline bf16x4 ld4b(const bf16_t* p) { return *(const bf16x4*)p; }

// ---------------- Kernel 1: node linear layers ----------------
// grid (768, 4): row x matrix; block 128
template<typename T>
__device__ void node_body(float* x,
    const T* h_nodes, const T* Uw, const T* Ub, const T* Vw, const T* Vb,
    const T* Aw, const T* Ab, const T* Bw, const T* Bb, const T* Cb,
    float* ws)
{
    const int row = blockIdx.x, m = blockIdx.y, t = threadIdx.x;
    x[t] = (float)h_nodes[row * HD + t];
    __syncthreads();

    const T* Ws[4] = {Aw, Bw, Vw, Uw};
    float bias;
    if (m == 0)      bias = (float)Ab[t] + (float)Cb[t];
    else if (m == 1) bias = (float)Bb[t];
    else if (m == 2) bias = (float)Vb[t];
    else             bias = (float)Ub[t];

    float acc = bias;
    const T* W = Ws[m] + (size_t)t * HD;
    #pragma unroll
    for (int kk = 0; kk < 16; ++kk) {
        float w8[8];
        ld8(W + kk * 8, w8);
        #pragma unroll
        for (int e = 0; e < 8; ++e) acc = fmaf(x[kk * 8 + e], w8[e], acc);
    }
    ws[m * SZ + row * HD + t] = acc;
}

__global__ __launch_bounds__(128) void node_linear(
    const void* h_nodes, const void* Uw, const void* Ub, const void* Vw, const void* Vb,
    const void* Aw, const void* Ab, const void* Bw, const void* Bb, const void* Cb,
    float* __restrict__ ws)
{
    __shared__ __align__(16) float x[HD];
    if (read_flag(ws))
        node_body<float>(x, (const float*)h_nodes, (const float*)Uw, (const float*)Ub,
                         (const float*)Vw, (const float*)Vb, (const float*)Aw, (const float*)Ab,
                         (const float*)Bw, (const float*)Bb, (const float*)Cb, ws);
    else
        node_body<bf16_t>(x, (const bf16_t*)h_nodes, (const bf16_t*)Uw, (const bf16_t*)Ub,
                          (const bf16_t*)Vw, (const bf16_t*)Vb, (const bf16_t*)Aw, (const bf16_t*)Ab,
                          (const bf16_t*)Bw, (const bf16_t*)Bb, (const bf16_t*)Cb, ws);
}

// ---------------- Kernel 2: edge pipeline; TWO 16-j tiles per wave; Cw in LDS ----------------
// grid (384, JC, 2); block 256 = 4 waves.
// D = Cw * E^T: lane holds j; h = ct*16 + (l>>4)*4 + r (in registers).
// Order: LDS writes -> barrier -> prefetch A -> K-loop (both tiles share Bf reads)
//        -> [issue B loads] epilogue A -> epilogue B -> DPP reduce -> wagg.
struct Smem {
    bf16_t sCw[128 * 128];      // swizzled: row*256B + ((slot ^ (row&15))*16B)
    float sAhC[HD], sGe[HD], sBe[HD];
    float sAgg[4][HD];
};

template<typename T>
__device__ void edge_body(Smem& sm,
    const T* __restrict__ h_edges, const T* __restrict__ adj,
    const T* __restrict__ Cw, const T* __restrict__ ge, const T* __restrict__ be,
    const float* __restrict__ ws, float* __restrict__ wagg, float* __restrict__ out)
{
    const int i = blockIdx.x, jc = blockIdx.y, b = blockIdx.z;
    const int bi = b * NN + i;
    const int t = threadIdx.x;
    const int l = t & 63, w = t >> 6;
    const int lr = l & 15, lg = l >> 4;
    const int hbase = lg * 4;

    // ---- stage Cw into LDS, swizzled; 16 threads per row -> contiguous 256B reads ----
    {
        const int slot = t & 15;
        #pragma unroll
        for (int p = 0; p < 8; ++p) {
            const int row = p * 16 + (t >> 4);
            bf16x8 v = ld8b(&Cw[(size_t)row * HD + slot * 8]);
            *(bf16x8*)((char*)sm.sCw + row * 256 + ((slot ^ (row & 15)) << 4)) = v;
        }
    }
    if (t < HD) {
        sm.sAhC[t] = ws[0 * SZ + bi * HD + t];
        sm.sGe[t]  = (float)ge[t];
        sm.sBe[t]  = (float)be[t];
    }

    __syncthreads();   // drains only the staging; all prefetch comes AFTER

    const T* Ebase = h_edges + (size_t)bi * NN * HD;
    const int j0 = jc * 128 + w * 32;
    const int jA = j0 + lr, jB = j0 + 16 + lr;
    const T* ErowA = &Ebase[(size_t)jA * HD];
    const T* ErowB = &Ebase[(size_t)jB * HD];

    // ---- prefetch tile A: mask + residual + Bh/Vh (hide under K-loop) ----
    const float mkA = (float)adj[(size_t)bi * NN + jA];
    const float mkB = (float)adj[(size_t)bi * NN + jB];
    bf16x4 resA[8];
    #pragma unroll
    for (int ct = 0; ct < 8; ++ct)
        resA[ct] = ld4b(&ErowA[ct * 16 + hbase]);
    const float* BhA = ws + 1 * SZ + ((size_t)b * NN + jA) * HD;
    const float* VhA = ws + 2 * SZ + ((size_t)b * NN + jA) * HD;
    f32x4 bhvA[8], vhvA[8];
    #pragma unroll
    for (int ct = 0; ct < 8; ++ct) {
        bhvA[ct] = *(const f32x4*)&BhA[ct * 16 + hbase];
        vhvA[ct] = *(const f32x4*)&VhA[ct * 16 + hbase];
    }

    // ---- K-loop: per ks, 8 ds_read_b128 (Bf, shared) + 2 global A-frags, 16 MFMA ----
    f32x4 acc0[8], acc1[8];
    #pragma unroll
    for (int ct = 0; ct < 8; ++ct) {
        acc0[ct] = (f32x4){0.f, 0.f, 0.f, 0.f};
        acc1[ct] = (f32x4){0.f, 0.f, 0.f, 0.f};
    }
    #pragma unroll
    for (int ks = 0; ks < 4; ++ks) {
        bf16x8 a0 = ld8b(&ErowA[ks * 32 + lg * 8]);
        bf16x8 a1 = ld8b(&ErowB[ks * 32 + lg * 8]);
        #pragma unroll
        for (int ct = 0; ct < 8; ++ct) {
            bf16x8 Bf = *(const bf16x8*)((const char*)sm.sCw +
                          (ct * 16 + lr) * 256 + ((((ks << 2) | lg) ^ lr) << 4));
            acc0[ct] = __builtin_amdgcn_mfma_f32_16x16x32_bf16(Bf, a0, acc0[ct], 0, 0, 0);
            acc1[ct] = __builtin_amdgcn_mfma_f32_16x16x32_bf16(Bf, a1, acc1[ct], 0, 0, 0);
        }
    }

    // ---- issue tile B loads (fly under epilogue A's VALU) ----
    bf16x4 resB[8];
    #pragma unroll
    for (int ct = 0; ct < 8; ++ct)
        resB[ct] = ld4b(&ErowB[ct * 16 + hbase]);
    const float* BhB = ws + 1 * SZ + ((size_t)b * NN + jB) * HD;
    const float* VhB = ws + 2 * SZ + ((size_t)b * NN + jB) * HD;
    f32x4 bhvB[8], vhvB[8];
    #pragma unroll
    for (int ct = 0; ct < 8; ++ct) {
        bhvB[ct] = *(const f32x4*)&BhB[ct * 16 + hbase];
        vhvB[ct] = *(const f32x4*)&VhB[ct * 16 + hbase];
    }

    f32x4 agg4[8];
    #pragma unroll
    for (int ct = 0; ct < 8; ++ct) agg4[ct] = (f32x4){0.f, 0.f, 0.f, 0.f};

    // ---- epilogue A ----
    {
        float* Orow = out + SZ + ((size_t)bi * NN + jA) * HD;
        float sum = 0.f, ssq = 0.f;
        #pragma unroll
        for (int ct = 0; ct < 8; ++ct) {
            f32x4 e = acc0[ct];
            f32x4 av = *(const f32x4*)&sm.sAhC[ct * 16 + hbase];
            e = e + av + bhvA[ct];
            acc0[ct] = e;
            #pragma unroll
            for (int r = 0; r < 4; ++r) { sum += e[r]; ssq = fmaf(e[r], e[r], ssq); }
        }
        sum += __shfl_xor(sum, 16); ssq += __shfl_xor(ssq, 16);
        sum += __shfl_xor(sum, 32); ssq += __shfl_xor(ssq, 32);
        const float mean = sum * (1.f / HD);
        const float rstd = rsqrtf(ssq * (1.f / HD) - mean * mean + 1e-5f);
        #pragma unroll
        for (int ct = 0; ct < 8; ++ct) {
            f32x4 ge4 = *(const f32x4*)&sm.sGe[ct * 16 + hbase];
            f32x4 be4 = *(const f32x4*)&sm.sBe[ct * 16 + hbase];
            f32x4 o;
            #pragma unroll
            for (int r = 0; r < 4; ++r) {
                const float ee = acc0[ct][r];
                const float g = 1.f / (1.f + exp2f(ee * -1.44269504f));
                agg4[ct][r] = fmaf(g * mkA, vhvA[ct][r], agg4[ct][r]);
                float a = (ee - mean) * rstd;
                a = fmaf(a, ge4[r], be4[r]);
                a = fmaxf(a, 0.f);
                o[r] = (float)resA[ct][r] + a;
            }
            *(f32x4*)&Orow[ct * 16 + hbase] = o;
        }
    }

    // ---- epilogue B ----
    {
        float* Orow = out + SZ + ((size_t)bi * NN + jB) * HD;
        float sum = 0.f, ssq = 0.f;
        #pragma unroll
        for (int ct = 0; ct < 8; ++ct) {
            f32x4 e = acc1[ct];
            f32x4 av = *(const f32x4*)&sm.sAhC[ct * 16 + hbase];
            e = e + av + bhvB[ct];
            acc1[ct] = e;
            #pragma unroll
            for (int r = 0; r < 4; ++r) { sum += e[r]; ssq = fmaf(e[r], e[r], ssq); }
        }
        sum += __shfl_xor(sum, 16); ssq += __shfl_xor(ssq, 16);
        sum += __shfl_xor(sum, 32); ssq += __shfl_xor(ssq, 32);
        const float mean = sum * (1.f / HD);
        const float rstd = rsqrtf(ssq * (1.f / HD) - mean * mean + 1e-5f);
        #pragma unroll
        for (int ct = 0; ct < 8; ++ct) {
            f32x4 ge4 = *(const f32x4*)&sm.sGe[ct * 16 + hbase];
            f32x4 be4 = *(const f32x4*)&sm.sBe[ct * 16 + hbase];
            f32x4 o;
            #pragma unroll
            for (int r = 0; r < 4; ++r) {
                const float ee = acc1[ct][r];
                const float g = 1.f / (1.f + exp2f(ee * -1.44269504f));
                agg4[ct][r] = fmaf(g * mkB, vhvB[ct][r], agg4[ct][r]);
                float a = (ee - mean) * rstd;
                a = fmaf(a, ge4[r], be4[r]);
                a = fmaxf(a, 0.f);
                o[r] = (float)resB[ct][r] + a;
            }
            *(f32x4*)&Orow[ct * 16 + hbase] = o;
        }
    }

    // ---- reduce agg over j-lanes (lr, 16-lane rows) via VALU DPP ----
    #pragma unroll
    for (int ct = 0; ct < 8; ++ct)
        #pragma unroll
        for (int r = 0; r < 4; ++r)
            agg4[ct][r] = row16_sum(agg4[ct][r]);
    if (lr == 0) {
        #pragma unroll
        for (int ct = 0; ct < 8; ++ct)
            *(f32x4*)&sm.sAgg[w][ct * 16 + hbase] = agg4[ct];
    }
    __syncthreads();

    // ---- per-block partial agg -> wagg ----
    if (t < HD) {
        float p = sm.sAgg[0][t] + sm.sAgg[1][t] + sm.sAgg[2][t] + sm.sAgg[3][t];
        wagg[((size_t)jc * ROWS + bi) * HD + t] = p;
    }
}

__global__ __launch_bounds__(256) void edge_kernel(
    const void* h_edges, const void* adj, const void* Cw,
    const void* ge, const void* be,
    float* __restrict__ ws, float* __restrict__ out)
{
    __shared__ Smem sm;
    float* wagg = ws + 4 * SZ;
    if (read_flag(ws))
        edge_body<float>(sm, (const float*)h_edges, (const float*)adj, (const float*)Cw,
                         (const float*)ge, (const float*)be, ws, wagg, out);
    else
        edge_body<bf16_t>(sm, (const bf16_t*)h_edges, (const bf16_t*)adj, (const bf16_t*)Cw,
                          (const bf16_t*)ge, (const bf16_t*)be, ws, wagg, out);
}

// ---------------- Kernel 3: node update ----------------
// grid 768; block 64 (one wave, 2 cols/lane)
template<typename T>
__device__ void node_upd_body(const T* h_nodes, const T* gh, const T* bh,
                              const float* ws, float* out)
{
    const int bi = blockIdx.x, t = threadIdx.x;
    float x0 = ws[3 * SZ + bi * HD + t];
    float x1 = ws[3 * SZ + bi * HD + t + 64];
    #pragma unroll
    for (int jc = 0; jc < JC; ++jc) {
        const float* p = ws + 4 * SZ + ((size_t)jc * ROWS + bi) * HD;
        x0 += p[t];
        x1 += p[t + 64];
    }
    float sum = x0 + x1;
    float ssq = x0 * x0 + x1 * x1;
    #pragma unroll
    for (int off = 1; off < 64; off <<= 1) {
        sum += __shfl_xor(sum, off);
        ssq += __shfl_xor(ssq, off);
    }
    const float mean = sum * (1.f / HD);
    const float rstd = rsqrtf(ssq * (1.f / HD) - mean * mean + 1e-5f);
    float a0 = fmaf((x0 - mean) * rstd, (float)gh[t],      (float)bh[t]);
    float a1 = fmaf((x1 - mean) * rstd, (float)gh[t + 64], (float)bh[t + 64]);
    a0 = fmaxf(a0, 0.f);
    a1 = fmaxf(a1, 0.f);
    out[bi * HD + t]      = (float)h_nodes[bi * HD + t]      + a0;
    out[bi * HD + t + 64] = (float)h_nodes[bi * HD + t + 64] + a1;
}

__global__ __launch_bounds__(64) void node_update(
    const void* h_nodes, const void* gh, const void* bh,
    const float* __restrict__ ws, float* __restrict__ out)
{
    if (read_flag(ws))
        node_upd_body<float>((const float*)h_nodes, (const float*)gh, (const float*)bh, ws, out);
    else
        node_upd_body<bf16_t>((const bf16_t*)h_nodes, (const bf16_t*)gh, (const bf16_t*)bh, ws, out);
}

extern "C" void kernel_launch(void* const* d_in, const int* in_sizes, int n_in,
                              void* d_out, int out_size, void* d_ws, size_t ws_size,
                              hipStream_t stream)
{
    float* ws = (float*)d_ws;
    float* out = (float*)d_out;

    detect_kernel<<<dim3(1), dim3(64), 0, stream>>>(d_in[0], ws);
    node_linear<<<dim3(ROWS, 4), dim3(128), 0, stream>>>(
        d_in[0], d_in[3], d_in[4], d_in[5], d_in[6], d_in[7], d_in[8],
        d_in[9], d_in[10], d_in[12], ws);
    edge_kernel<<<dim3(NN, JC, 2), dim3(256), 0, stream>>>(
        d_in[1], d_in[2], d_in[11], d_in[15], d_in[16], ws, out);
    node_update<<<dim3(ROWS), dim3(64), 0, stream>>>(
        d_in[0], d_in[13], d_in[14], ws, out);
}

// Round 16
// 145.862 us; speedup vs baseline: 1.1319x; 1.1319x over previous
//
#include <hip/hip_runtime.h>
#include <hip/hip_bf16.h>

typedef __bf16 bf16_t;
typedef __bf16 bf16x8 __attribute__((ext_vector_type(8)));
typedef __bf16 bf16x4 __attribute__((ext_vector_type(4)));
typedef float f32x4 __attribute__((ext_vector_type(4)));

#define HD 128
#define NN 384
#define ROWS 768           // B*N
#define SZ 98304           // ROWS*HD
#define JC 3               // j-chunks per (b,i): block covers 128 j (8 waves x 16 j)
// ws f32 layout: [0..4*SZ) = AhC, Bh, Vh, Uh ; [4*SZ..7*SZ) = wagg [JC][ROWS][HD];
// flag at ws[7*SZ]

// ---- runtime input-dtype detector: 1 if buffer holds f32, 0 if bf16 ----
__device__ inline int detect_f32(const void* p) {
    const unsigned short* u = (const unsigned short*)p;
    int bad = 0;
    #pragma unroll
    for (int k = 0; k < 128; ++k) {
        int e = (u[k] >> 7) & 0xFF;
        bad += (e < 110 || e > 135) ? 1 : 0;
    }
    return bad >= 16 ? 1 : 0;
}

__global__ __launch_bounds__(64) void detect_kernel(const void* p, float* ws) {
    if (threadIdx.x == 0)
        *(int*)((char*)ws + (size_t)7 * SZ * 4) = detect_f32(p);
}

__device__ inline int read_flag(const float* ws) {
    return *(const int*)((const char*)ws + (size_t)7 * SZ * 4);
}

// ---- DPP 16-lane (row) sum reduction: quad_perm ^1, ^2 then row_ror 4, 8 ----
template<int CTRL>
__device__ __attribute__((always_inline)) inline float dpp_add(float x) {
    int xi = __builtin_bit_cast(int, x);
    int yi = __builtin_amdgcn_update_dpp(0, xi, CTRL, 0xF, 0xF, true);
    return x + __builtin_bit_cast(float, yi);
}
__device__ __attribute__((always_inline)) inline float row16_sum(float x) {
    x = dpp_add<0xB1>(x);    // quad_perm(1,0,3,2): ^1
    x = dpp_add<0x4E>(x);    // quad_perm(2,3,0,1): ^2
    x = dpp_add<0x124>(x);   // row_ror:4
    x = dpp_add<0x128>(x);   // row_ror:8
    return x;
}

// ---- dtype-generic load helpers ----
__device__ __attribute__((always_inline)) inline void ld8(const float* p, float* o) {
    f32x4 a = *(const f32x4*)p;
    f32x4 b = *(const f32x4*)(p + 4);
    o[0] = a[0]; o[1] = a[1]; o[2] = a[2]; o[3] = a[3];
    o[4] = b[0]; o[5] = b[1]; o[6] = b[2]; o[7] = b[3];
}
__device__ __attribute__((always_inline)) inline void ld8(const bf16_t* p, float* o) {
    bf16x8 v = *(const bf16x8*)p;
    #pragma unroll
    for (int e = 0; e < 8; ++e) o[e] = (float)v[e];
}
__device__ __attribute__((always_inline)) inline bf16x8 ld8b(const float* p) {
    f32x4 a = *(const f32x4*)p;
    f32x4 b = *(const f32x4*)(p + 4);
    bf16x8 v;
    #pragma unroll
    for (int e = 0; e < 4; ++e) { v[e] = (bf16_t)a[e]; v[e + 4] = (bf16_t)b[e]; }
    return v;
}
__device__ __attribute__((always_inline)) inline bf16x8 ld8b(const bf16_t* p) { return *(const bf16x8*)p; }
__device__ __attribute__((always_inline)) inline bf16x4 ld4b(const float* p) {
    f32x4 a = *(const f32x4*)p;
    bf16x4 v;
    #pragma unroll
    for (int e = 0; e < 4; ++e) v[e] = (bf16_t)a[e];
    return v;
}
__device__ __attribute__((always_inline)) inline bf16x4 ld4b(const bf16_t* p) { return *(const bf16x4*)p; }

// ---------------- Kernel 1: node linear layers ----------------
// grid (768, 4): row x matrix; block 128
template<typename T>
__device__ void node_body(float* x,
    const T* h_nodes, const T* Uw, const T* Ub, const T* Vw, const T* Vb,
    const T* Aw, const T* Ab, const T* Bw, const T* Bb, const T* Cb,
    float* ws)
{
    const int row = blockIdx.x, m = blockIdx.y, t = threadIdx.x;
    x[t] = (float)h_nodes[row * HD + t];
    __syncthreads();

    const T* Ws[4] = {Aw, Bw, Vw, Uw};
    float bias;
    if (m == 0)      bias = (float)Ab[t] + (float)Cb[t];
    else if (m == 1) bias = (float)Bb[t];
    else if (m == 2) bias = (float)Vb[t];
    else             bias = (float)Ub[t];

    float acc = bias;
    const T* W = Ws[m] + (size_t)t * HD;
    #pragma unroll
    for (int kk = 0; kk < 16; ++kk) {
        float w8[8];
        ld8(W + kk * 8, w8);
        #pragma unroll
        for (int e = 0; e < 8; ++e) acc = fmaf(x[kk * 8 + e], w8[e], acc);
    }
    ws[m * SZ + row * HD + t] = acc;
}

__global__ __launch_bounds__(128) void node_linear(
    const void* h_nodes, const void* Uw, const void* Ub, const void* Vw, const void* Vb,
    const void* Aw, const void* Ab, const void* Bw, const void* Bb, const void* Cb,
    float* __restrict__ ws)
{
    __shared__ __align__(16) float x[HD];
    if (read_flag(ws))
        node_body<float>(x, (const float*)h_nodes, (const float*)Uw, (const float*)Ub,
                         (const float*)Vw, (const float*)Vb, (const float*)Aw, (const float*)Ab,
                         (const float*)Bw, (const float*)Bb, (const float*)Cb, ws);
    else
        node_body<bf16_t>(x, (const bf16_t*)h_nodes, (const bf16_t*)Uw, (const bf16_t*)Ub,
                          (const bf16_t*)Vw, (const bf16_t*)Vb, (const bf16_t*)Aw, (const bf16_t*)Ab,
                          (const bf16_t*)Bw, (const bf16_t*)Bb, (const bf16_t*)Cb, ws);
}

// ---------------- Kernel 2: edge pipeline; one 16-j tile per wave; 8 waves/block ----------------
// grid (384, JC, 2); block 512 = 8 waves; Cw staged in LDS once per block (serves 128 j).
// D = Cw * E^T: lane holds j = jc*128 + w*16 + lr; h = ct*16 + (l>>4)*4 + r (in registers).
// Order: LDS writes -> barrier -> prefetch (res/Bh/Vh) -> K-loop -> epilogue.
struct Smem {
    bf16_t sCw[128 * 128];      // swizzled: row*256B + ((slot ^ (row&15))*16B)
    float sAhC[HD], sGe[HD], sBe[HD];
    float sAgg[8][HD];
};

template<typename T>
__device__ void edge_body(Smem& sm,
    const T* __restrict__ h_edges, const T* __restrict__ adj,
    const T* __restrict__ Cw, const T* __restrict__ ge, const T* __restrict__ be,
    const float* __restrict__ ws, float* __restrict__ wagg, float* __restrict__ out)
{
    const int i = blockIdx.x, jc = blockIdx.y, b = blockIdx.z;
    const int bi = b * NN + i;
    const int t = threadIdx.x;
    const int l = t & 63, w = t >> 6;
    const int lr = l & 15, lg = l >> 4;
    const int hbase = lg * 4;

    // ---- stage Cw into LDS, swizzled; 512 threads -> 4 rows each ----
    {
        const int slot = t & 15;
        #pragma unroll
        for (int p = 0; p < 4; ++p) {
            const int row = p * 32 + (t >> 4);
            bf16x8 v = ld8b(&Cw[(size_t)row * HD + slot * 8]);
            *(bf16x8*)((char*)sm.sCw + row * 256 + ((slot ^ (row & 15)) << 4)) = v;
        }
    }
    if (t < HD) {
        sm.sAhC[t] = ws[0 * SZ + bi * HD + t];
        sm.sGe[t]  = (float)ge[t];
        sm.sBe[t]  = (float)be[t];
    }

    __syncthreads();   // drains only the staging; prefetch comes AFTER (no barrier-drain)

    const T* Ebase = h_edges + (size_t)bi * NN * HD;
    const int j = jc * 128 + w * 16 + lr;
    const T* Erow = &Ebase[(size_t)j * HD];

    // ---- prefetch: mask + residual + Bh/Vh; latency hides under the K-loop ----
    const float mk = (float)adj[(size_t)bi * NN + j];
    bf16x4 res[8];
    #pragma unroll
    for (int ct = 0; ct < 8; ++ct)
        res[ct] = ld4b(&Erow[ct * 16 + hbase]);

    const float* Bhrow = ws + 1 * SZ + ((size_t)b * NN + j) * HD;
    const float* Vhrow = ws + 2 * SZ + ((size_t)b * NN + j) * HD;
    f32x4 bhv[8], vhv[8];
    #pragma unroll
    for (int ct = 0; ct < 8; ++ct) {
        bhv[ct] = *(const f32x4*)&Bhrow[ct * 16 + hbase];
        vhv[ct] = *(const f32x4*)&Vhrow[ct * 16 + hbase];
    }

    // ---- K-loop: per ks, 8 ds_read_b128 (Bf) + 1 global A-frag, 8 MFMA ----
    f32x4 acc[8];
    #pragma unroll
    for (int ct = 0; ct < 8; ++ct) acc[ct] = (f32x4){0.f, 0.f, 0.f, 0.f};
    #pragma unroll
    for (int ks = 0; ks < 4; ++ks) {
        bf16x8 a = ld8b(&Erow[ks * 32 + lg * 8]);
        #pragma unroll
        for (int ct = 0; ct < 8; ++ct) {
            bf16x8 Bf = *(const bf16x8*)((const char*)sm.sCw +
                          (ct * 16 + lr) * 256 + ((((ks << 2) | lg) ^ lr) << 4));
            acc[ct] = __builtin_amdgcn_mfma_f32_16x16x32_bf16(Bf, a, acc[ct], 0, 0, 0);
        }
    }

    // ---- inlined epilogue: e_upd = acc + AhC + Bh; LN over h; gate+agg; store ----
    float* Orow = out + SZ + ((size_t)bi * NN + j) * HD;

    float sum = 0.f, ssq = 0.f;
    #pragma unroll
    for (int ct = 0; ct < 8; ++ct) {
        f32x4 e = acc[ct];
        f32x4 av = *(const f32x4*)&sm.sAhC[ct * 16 + hbase];
        e = e + av + bhv[ct];
        acc[ct] = e;
        #pragma unroll
        for (int r = 0; r < 4; ++r) { sum += e[r]; ssq = fmaf(e[r], e[r], ssq); }
    }
    sum += __shfl_xor(sum, 16); ssq += __shfl_xor(ssq, 16);
    sum += __shfl_xor(sum, 32); ssq += __shfl_xor(ssq, 32);
    const float mean = sum * (1.f / HD);
    const float rstd = rsqrtf(ssq * (1.f / HD) - mean * mean + 1e-5f);

    f32x4 agg4[8];
    #pragma unroll
    for (int ct = 0; ct < 8; ++ct) {
        f32x4 ge4 = *(const f32x4*)&sm.sGe[ct * 16 + hbase];
        f32x4 be4 = *(const f32x4*)&sm.sBe[ct * 16 + hbase];
        f32x4 o;
        #pragma unroll
        for (int r = 0; r < 4; ++r) {
            const float ee = acc[ct][r];
            const float g = 1.f / (1.f + exp2f(ee * -1.44269504f));
            agg4[ct][r] = g * mk * vhv[ct][r];
            float a = (ee - mean) * rstd;
            a = fmaf(a, ge4[r], be4[r]);
            a = fmaxf(a, 0.f);
            o[r] = (float)res[ct][r] + a;
        }
        *(f32x4*)&Orow[ct * 16 + hbase] = o;
    }

    // ---- reduce agg over j-lanes (lr, 16-lane rows) via VALU DPP ----
    #pragma unroll
    for (int ct = 0; ct < 8; ++ct)
        #pragma unroll
        for (int r = 0; r < 4; ++r)
            agg4[ct][r] = row16_sum(agg4[ct][r]);
    if (lr == 0) {
        #pragma unroll
        for (int ct = 0; ct < 8; ++ct)
            *(f32x4*)&sm.sAgg[w][ct * 16 + hbase] = agg4[ct];
    }
    __syncthreads();

    // ---- per-block partial agg -> wagg ----
    if (t < HD) {
        float p = sm.sAgg[0][t] + sm.sAgg[1][t] + sm.sAgg[2][t] + sm.sAgg[3][t]
                + sm.sAgg[4][t] + sm.sAgg[5][t] + sm.sAgg[6][t] + sm.sAgg[7][t];
        wagg[((size_t)jc * ROWS + bi) * HD + t] = p;
    }
}

__global__ __launch_bounds__(512) void edge_kernel(
    const void* h_edges, const void* adj, const void* Cw,
    const void* ge, const void* be,
    float* __restrict__ ws, float* __restrict__ out)
{
    __shared__ Smem sm;
    float* wagg = ws + 4 * SZ;
    if (read_flag(ws))
        edge_body<float>(sm, (const float*)h_edges, (const float*)adj, (const float*)Cw,
                         (const float*)ge, (const float*)be, ws, wagg, out);
    else
        edge_body<bf16_t>(sm, (const bf16_t*)h_edges, (const bf16_t*)adj, (const bf16_t*)Cw,
                          (const bf16_t*)ge, (const bf16_t*)be, ws, wagg, out);
}

// ---------------- Kernel 3: node update ----------------
// grid 768; block 64 (one wave, 2 cols/lane)
template<typename T>
__device__ void node_upd_body(const T* h_nodes, const T* gh, const T* bh,
                              const float* ws, float* out)
{
    const int bi = blockIdx.x, t = threadIdx.x;
    float x0 = ws[3 * SZ + bi * HD + t];
    float x1 = ws[3 * SZ + bi * HD + t + 64];
    #pragma unroll
    for (int jc = 0; jc < JC; ++jc) {
        const float* p = ws + 4 * SZ + ((size_t)jc * ROWS + bi) * HD;
        x0 += p[t];
        x1 += p[t + 64];
    }
    float sum = x0 + x1;
    float ssq = x0 * x0 + x1 * x1;
    #pragma unroll
    for (int off = 1; off < 64; off <<= 1) {
        sum += __shfl_xor(sum, off);
        ssq += __shfl_xor(ssq, off);
    }
    const float mean = sum * (1.f / HD);
    const float rstd = rsqrtf(ssq * (1.f / HD) - mean * mean + 1e-5f);
    float a0 = fmaf((x0 - mean) * rstd, (float)gh[t],      (float)bh[t]);
    float a1 = fmaf((x1 - mean) * rstd, (float)gh[t + 64], (float)bh[t + 64]);
    a0 = fmaxf(a0, 0.f);
    a1 = fmaxf(a1, 0.f);
    out[bi * HD + t]      = (float)h_nodes[bi * HD + t]      + a0;
    out[bi * HD + t + 64] = (float)h_nodes[bi * HD + t + 64] + a1;
}

__global__ __launch_bounds__(64) void node_update(
    const void* h_nodes, const void* gh, const void* bh,
    const float* __restrict__ ws, float* __restrict__ out)
{
    if (read_flag(ws))
        node_upd_body<float>((const float*)h_nodes, (const float*)gh, (const float*)bh, ws, out);
    else
        node_upd_body<bf16_t>((const bf16_t*)h_nodes, (const bf16_t*)gh, (const bf16_t*)bh, ws, out);
}

extern "C" void kernel_launch(void* const* d_in, const int* in_sizes, int n_in,
                              void* d_out, int out_size, void* d_ws, size_t ws_size,
                              hipStream_t stream)
{
    float* ws = (float*)d_ws;
    float* out = (float*)d_out;

    detect_kernel<<<dim3(1), dim3(64), 0, stream>>>(d_in[0], ws);
    node_linear<<<dim3(ROWS, 4), dim3(128), 0, stream>>>(
        d_in[0], d_in[3], d_in[4], d_in[5], d_in[6], d_in[7], d_in[8],
        d_in[9], d_in[10], d_in[12], ws);
    edge_kernel<<<dim3(NN, JC, 2), dim3(512), 0, stream>>>(
        d_in[1], d_in[2], d_in[11], d_in[15], d_in[16], ws, out);
    node_update<<<dim3(ROWS), dim3(64), 0, stream>>>(
        d_in[0], d_in[13], d_in[14], ws, out);
}

// Round 17
// 141.624 us; speedup vs baseline: 1.1658x; 1.0299x over previous
//
#include <hip/hip_runtime.h>
#include <hip/hip_bf16.h>

typedef __bf16 bf16_t;
typedef __bf16 bf16x8 __attribute__((ext_vector_type(8)));
typedef __bf16 bf16x4 __attribute__((ext_vector_type(4)));
typedef float f32x4 __attribute__((ext_vector_type(4)));

#define HD 128
#define NN 384
#define ROWS 768           // B*N
#define SZ 98304           // ROWS*HD
#define JC 6               // j-chunks per (b,i): block covers 64 j, wave covers 16 j
#define CWPITCH 272        // bytes per sCw row: 256 + 16 pad -> conflict-free ds_read_b128
// ws f32 layout: [0..4*SZ) = AhC, Bh, Vh, Uh ; [4*SZ..10*SZ) = wagg [JC][ROWS][HD];
// flag at ws[10*SZ]

// ---- runtime input-dtype detector: 1 if buffer holds f32, 0 if bf16 ----
__device__ inline int detect_f32(const void* p) {
    const unsigned short* u = (const unsigned short*)p;
    int bad = 0;
    #pragma unroll
    for (int k = 0; k < 128; ++k) {
        int e = (u[k] >> 7) & 0xFF;
        bad += (e < 110 || e > 135) ? 1 : 0;
    }
    return bad >= 16 ? 1 : 0;
}

__global__ __launch_bounds__(64) void detect_kernel(const void* p, float* ws) {
    if (threadIdx.x == 0)
        *(int*)((char*)ws + (size_t)10 * SZ * 4) = detect_f32(p);
}

__device__ inline int read_flag(const float* ws) {
    return *(const int*)((const char*)ws + (size_t)10 * SZ * 4);
}

// ---- DPP 16-lane (row) sum reduction: quad_perm ^1, ^2 then row_ror 4, 8 ----
template<int CTRL>
__device__ __attribute__((always_inline)) inline float dpp_add(float x) {
    int xi = __builtin_bit_cast(int, x);
    int yi = __builtin_amdgcn_update_dpp(0, xi, CTRL, 0xF, 0xF, true);
    return x + __builtin_bit_cast(float, yi);
}
__device__ __attribute__((always_inline)) inline float row16_sum(float x) {
    x = dpp_add<0xB1>(x);    // quad_perm(1,0,3,2): ^1
    x = dpp_add<0x4E>(x);    // quad_perm(2,3,0,1): ^2
    x = dpp_add<0x124>(x);   // row_ror:4
    x = dpp_add<0x128>(x);   // row_ror:8
    return x;
}

// ---- dtype-generic load helpers ----
__device__ __attribute__((always_inline)) inline void ld8(const float* p, float* o) {
    f32x4 a = *(const f32x4*)p;
    f32x4 b = *(const f32x4*)(p + 4);
    o[0] = a[0]; o[1] = a[1]; o[2] = a[2]; o[3] = a[3];
    o[4] = b[0]; o[5] = b[1]; o[6] = b[2]; o[7] = b[3];
}
__device__ __attribute__((always_inline)) inline void ld8(const bf16_t* p, float* o) {
    bf16x8 v = *(const bf16x8*)p;
    #pragma unroll
    for (int e = 0; e < 8; ++e) o[e] = (float)v[e];
}
__device__ __attribute__((always_inline)) inline bf16x8 ld8b(const float* p) {
    f32x4 a = *(const f32x4*)p;
    f32x4 b = *(const f32x4*)(p + 4);
    bf16x8 v;
    #pragma unroll
    for (int e = 0; e < 4; ++e) { v[e] = (bf16_t)a[e]; v[e + 4] = (bf16_t)b[e]; }
    return v;
}
__device__ __attribute__((always_inline)) inline bf16x8 ld8b(const bf16_t* p) { return *(const bf16x8*)p; }
__device__ __attribute__((always_inline)) inline bf16x4 ld4b(const float* p) {
    f32x4 a = *(const f32x4*)p;
    bf16x4 v;
    #pragma unroll
    for (int e = 0; e < 4; ++e) v[e] = (bf16_t)a[e];
    return v;
}
__device__ __attribute__((always_inline)) inline bf16x4 ld4b(const bf16_t* p) { return *(const bf16x4*)p; }

// ---------------- Kernel 1: node linear layers ----------------
// grid (768, 4): row x matrix; block 128
template<typename T>
__device__ void node_body(float* x,
    const T* h_nodes, const T* Uw, const T* Ub, const T* Vw, const T* Vb,
    const T* Aw, const T* Ab, const T* Bw, const T* Bb, const T* Cb,
    float* ws)
{
    const int row = blockIdx.x, m = blockIdx.y, t = threadIdx.x;
    x[t] = (float)h_nodes[row * HD + t];
    __syncthreads();

    const T* Ws[4] = {Aw, Bw, Vw, Uw};
    float bias;
    if (m == 0)      bias = (float)Ab[t] + (float)Cb[t];
    else if (m == 1) bias = (float)Bb[t];
    else if (m == 2) bias = (float)Vb[t];
    else             bias = (float)Ub[t];

    float acc = bias;
    const T* W = Ws[m] + (size_t)t * HD;
    #pragma unroll
    for (int kk = 0; kk < 16; ++kk) {
        float w8[8];
        ld8(W + kk * 8, w8);
        #pragma unroll
        for (int e = 0; e < 8; ++e) acc = fmaf(x[kk * 8 + e], w8[e], acc);
    }
    ws[m * SZ + row * HD + t] = acc;
}

__global__ __launch_bounds__(128) void node_linear(
    const void* h_nodes, const void* Uw, const void* Ub, const void* Vw, const void* Vb,
    const void* Aw, const void* Ab, const void* Bw, const void* Bb, const void* Cb,
    float* __restrict__ ws)
{
    __shared__ __align__(16) float x[HD];
    if (read_flag(ws))
        node_body<float>(x, (const float*)h_nodes, (const float*)Uw, (const float*)Ub,
                         (const float*)Vw, (const float*)Vb, (const float*)Aw, (const float*)Ab,
                         (const float*)Bw, (const float*)Bb, (const float*)Cb, ws);
    else
        node_body<bf16_t>(x, (const bf16_t*)h_nodes, (const bf16_t*)Uw, (const bf16_t*)Ub,
                          (const bf16_t*)Vw, (const bf16_t*)Vb, (const bf16_t*)Aw, (const bf16_t*)Ab,
                          (const bf16_t*)Bw, (const bf16_t*)Bb, (const bf16_t*)Cb, ws);
}

// ---------------- Kernel 2: edge pipeline; one 16-j tile per wave; Cw in LDS ----------------
// grid (384, JC, 2); block 256 = 4 waves.
// D = Cw * E^T: lane holds j = jc*64 + w*16 + lr; h = ct*16 + (l>>4)*4 + r (in registers).
// sCw row pitch 272B: bank group = (row*68 + slot*4)%32 -> 16 rows spread 8 groups, 2-way max.
struct Smem {
    bf16_t sCw[128 * (CWPITCH / 2)];
    float sAhC[HD], sGe[HD], sBe[HD];
    float sAgg[4][HD];
};

template<typename T>
__device__ void edge_body(Smem& sm,
    const T* __restrict__ h_edges, const T* __restrict__ adj,
    const T* __restrict__ Cw, const T* __restrict__ ge, const T* __restrict__ be,
    const float* __restrict__ ws, float* __restrict__ wagg, float* __restrict__ out)
{
    const int i = blockIdx.x, jc = blockIdx.y, b = blockIdx.z;
    const int bi = b * NN + i;
    const int t = threadIdx.x;
    const int l = t & 63, w = t >> 6;
    const int lr = l & 15, lg = l >> 4;
    const int hbase = lg * 4;

    // ---- stage Cw into LDS (padded rows); 16 threads per row -> contiguous 256B reads ----
    {
        const int slot = t & 15;
        #pragma unroll
        for (int p = 0; p < 8; ++p) {
            const int row = p * 16 + (t >> 4);
            bf16x8 v = ld8b(&Cw[(size_t)row * HD + slot * 8]);
            *(bf16x8*)((char*)sm.sCw + row * CWPITCH + slot * 16) = v;
        }
    }
    if (t < HD) {
        sm.sAhC[t] = ws[0 * SZ + bi * HD + t];
        sm.sGe[t]  = (float)ge[t];
        sm.sBe[t]  = (float)be[t];
    }

    __syncthreads();   // drains only the staging; prefetch comes AFTER (no barrier-drain)

    const T* Ebase = h_edges + (size_t)bi * NN * HD;
    const int j = jc * 64 + w * 16 + lr;
    const T* Erow = &Ebase[(size_t)j * HD];

    // ---- prefetch: mask + residual + Bh/Vh; latency hides under the K-loop ----
    const float mk = (float)adj[(size_t)bi * NN + j];
    bf16x4 res[8];
    #pragma unroll
    for (int ct = 0; ct < 8; ++ct)
        res[ct] = ld4b(&Erow[ct * 16 + hbase]);

    const float* Bhrow = ws + 1 * SZ + ((size_t)b * NN + j) * HD;
    const float* Vhrow = ws + 2 * SZ + ((size_t)b * NN + j) * HD;
    f32x4 bhv[8], vhv[8];
    #pragma unroll
    for (int ct = 0; ct < 8; ++ct) {
        bhv[ct] = *(const f32x4*)&Bhrow[ct * 16 + hbase];
        vhv[ct] = *(const f32x4*)&Vhrow[ct * 16 + hbase];
    }

    // ---- K-loop: per ks, 8 ds_read_b128 (Bf) + 1 global A-frag, 8 MFMA ----
    f32x4 acc[8];
    #pragma unroll
    for (int ct = 0; ct < 8; ++ct) acc[ct] = (f32x4){0.f, 0.f, 0.f, 0.f};
    #pragma unroll
    for (int ks = 0; ks < 4; ++ks) {
        bf16x8 a = ld8b(&Erow[ks * 32 + lg * 8]);
        #pragma unroll
        for (int ct = 0; ct < 8; ++ct) {
            bf16x8 Bf = *(const bf16x8*)((const char*)sm.sCw +
                          (ct * 16 + lr) * CWPITCH + (((ks << 2) | lg)) * 16);
            acc[ct] = __builtin_amdgcn_mfma_f32_16x16x32_bf16(Bf, a, acc[ct], 0, 0, 0);
        }
    }

    // ---- inlined epilogue: e_upd = acc + AhC + Bh; LN over h; gate+agg; store ----
    float* Orow = out + SZ + ((size_t)bi * NN + j) * HD;

    float sum = 0.f, ssq = 0.f;
    #pragma unroll
    for (int ct = 0; ct < 8; ++ct) {
        f32x4 e = acc[ct];
        f32x4 av = *(const f32x4*)&sm.sAhC[ct * 16 + hbase];
        e = e + av + bhv[ct];
        acc[ct] = e;
        #pragma unroll
        for (int r = 0; r < 4; ++r) { sum += e[r]; ssq = fmaf(e[r], e[r], ssq); }
    }
    sum += __shfl_xor(sum, 16); ssq += __shfl_xor(ssq, 16);
    sum += __shfl_xor(sum, 32); ssq += __shfl_xor(ssq, 32);
    const float mean = sum * (1.f / HD);
    const float rstd = rsqrtf(ssq * (1.f / HD) - mean * mean + 1e-5f);

    f32x4 agg4[8];
    #pragma unroll
    for (int ct = 0; ct < 8; ++ct) {
        f32x4 ge4 = *(const f32x4*)&sm.sGe[ct * 16 + hbase];
        f32x4 be4 = *(const f32x4*)&sm.sBe[ct * 16 + hbase];
        f32x4 o;
        #pragma unroll
        for (int r = 0; r < 4; ++r) {
            const float ee = acc[ct][r];
            const float g = 1.f / (1.f + exp2f(ee * -1.44269504f));
            agg4[ct][r] = g * mk * vhv[ct][r];
            float a = (ee - mean) * rstd;
            a = fmaf(a, ge4[r], be4[r]);
            a = fmaxf(a, 0.f);
            o[r] = (float)res[ct][r] + a;
        }
        *(f32x4*)&Orow[ct * 16 + hbase] = o;
    }

    // ---- reduce agg over j-lanes (lr, 16-lane rows) via VALU DPP ----
    #pragma unroll
    for (int ct = 0; ct < 8; ++ct)
        #pragma unroll
        for (int r = 0; r < 4; ++r)
            agg4[ct][r] = row16_sum(agg4[ct][r]);
    if (lr == 0) {
        #pragma unroll
        for (int ct = 0; ct < 8; ++ct)
            *(f32x4*)&sm.sAgg[w][ct * 16 + hbase] = agg4[ct];
    }
    __syncthreads();

    // ---- per-block partial agg -> wagg ----
    if (t < HD) {
        float p = sm.sAgg[0][t] + sm.sAgg[1][t] + sm.sAgg[2][t] + sm.sAgg[3][t];
        wagg[((size_t)jc * ROWS + bi) * HD + t] = p;
    }
}

__global__ __launch_bounds__(256) void edge_kernel(
    const void* h_edges, const void* adj, const void* Cw,
    const void* ge, const void* be,
    float* __restrict__ ws, float* __restrict__ out)
{
    __shared__ Smem sm;
    float* wagg = ws + 4 * SZ;
    if (read_flag(ws))
        edge_body<float>(sm, (const float*)h_edges, (const float*)adj, (const float*)Cw,
                         (const float*)ge, (const float*)be, ws, wagg, out);
    else
        edge_body<bf16_t>(sm, (const bf16_t*)h_edges, (const bf16_t*)adj, (const bf16_t*)Cw,
                          (const bf16_t*)ge, (const bf16_t*)be, ws, wagg, out);
}

// ---------------- Kernel 3: node update ----------------
// grid 768; block 64 (one wave, 2 cols/lane)
template<typename T>
__device__ void node_upd_body(const T* h_nodes, const T* gh, const T* bh,
                              const float* ws, float* out)
{
    const int bi = blockIdx.x, t = threadIdx.x;
    float x0 = ws[3 * SZ + bi * HD + t];
    float x1 = ws[3 * SZ + bi * HD + t + 64];
    #pragma unroll
    for (int jc = 0; jc < JC; ++jc) {
        const float* p = ws + 4 * SZ + ((size_t)jc * ROWS + bi) * HD;
        x0 += p[t];
        x1 += p[t + 64];
    }
    float sum = x0 + x1;
    float ssq = x0 * x0 + x1 * x1;
    #pragma unroll
    for (int off = 1; off < 64; off <<= 1) {
        sum += __shfl_xor(sum, off);
        ssq += __shfl_xor(ssq, off);
    }
    const float mean = sum * (1.f / HD);
    const float rstd = rsqrtf(ssq * (1.f / HD) - mean * mean + 1e-5f);
    float a0 = fmaf((x0 - mean) * rstd, (float)gh[t],      (float)bh[t]);
    float a1 = fmaf((x1 - mean) * rstd, (float)gh[t + 64], (float)bh[t + 64]);
    a0 = fmaxf(a0, 0.f);
    a1 = fmaxf(a1, 0.f);
    out[bi * HD + t]      = (float)h_nodes[bi * HD + t]      + a0;
    out[bi * HD + t + 64] = (float)h_nodes[bi * HD + t + 64] + a1;
}

__global__ __launch_bounds__(64) void node_update(
    const void* h_nodes, const void* gh, const void* bh,
    const float* __restrict__ ws, float* __restrict__ out)
{
    if (read_flag(ws))
        node_upd_body<float>((const float*)h_nodes, (const float*)gh, (const float*)bh, ws, out);
    else
        node_upd_body<bf16_t>((const bf16_t*)h_nodes, (const bf16_t*)gh, (const bf16_t*)bh, ws, out);
}

extern "C" void kernel_launch(void* const* d_in, const int* in_sizes, int n_in,
                              void* d_out, int out_size, void* d_ws, size_t ws_size,
                              hipStream_t stream)
{
    float* ws = (float*)d_ws;
    float* out = (float*)d_out;

    detect_kernel<<<dim3(1), dim3(64), 0, stream>>>(d_in[0], ws);
    node_linear<<<dim3(ROWS, 4), dim3(128), 0, stream>>>(
        d_in[0], d_in[3], d_in[4], d_in[5], d_in[6], d_in[7], d_in[8],
        d_in[9], d_in[10], d_in[12], ws);
    edge_kernel<<<dim3(NN, JC, 2), dim3(256), 0, stream>>>(
        d_in[1], d_in[2], d_in[11], d_in[15], d_in[16], ws, out);
    node_update<<<dim3(ROWS), dim3(64), 0, stream>>>(
        d_in[0], d_in[13], d_in[14], ws, out);
}

// Round 18
// 140.507 us; speedup vs baseline: 1.1750x; 1.0079x over previous
//
#include <hip/hip_runtime.h>
#include <hip/hip_bf16.h>

typedef __bf16 bf16_t;
typedef __bf16 bf16x8 __attribute__((ext_vector_type(8)));
typedef __bf16 bf16x4 __attribute__((ext_vector_type(4)));
typedef float f32x4 __attribute__((ext_vector_type(4)));

#define HD 128
#define NN 384
#define ROWS 768           // B*N
#define SZ 98304           // ROWS*HD
#define JC 6               // j-chunks per (b,i): block covers 64 j, wave covers 16 j
#define CWPITCH 272        // bytes per sCw row: 256 + 16 pad
// ws f32 layout: [0..4*SZ) = AhC, Bh, Vh, Uh ; [4*SZ..10*SZ) = wagg [JC][ROWS][HD];
// flag at ws[10*SZ]

// ---- runtime input-dtype detector: 1 if buffer holds f32, 0 if bf16 ----
__device__ inline int detect_f32(const void* p) {
    const unsigned short* u = (const unsigned short*)p;
    int bad = 0;
    #pragma unroll
    for (int k = 0; k < 128; ++k) {
        int e = (u[k] >> 7) & 0xFF;
        bad += (e < 110 || e > 135) ? 1 : 0;
    }
    return bad >= 16 ? 1 : 0;
}

__global__ __launch_bounds__(64) void detect_kernel(const void* p, float* ws) {
    if (threadIdx.x == 0)
        *(int*)((char*)ws + (size_t)10 * SZ * 4) = detect_f32(p);
}

__device__ inline int read_flag(const float* ws) {
    return *(const int*)((const char*)ws + (size_t)10 * SZ * 4);
}

// ---- DPP 16-lane (row) sum reduction: quad_perm ^1, ^2 then row_ror 4, 8 ----
template<int CTRL>
__device__ __attribute__((always_inline)) inline float dpp_add(float x) {
    int xi = __builtin_bit_cast(int, x);
    int yi = __builtin_amdgcn_update_dpp(0, xi, CTRL, 0xF, 0xF, true);
    return x + __builtin_bit_cast(float, yi);
}
__device__ __attribute__((always_inline)) inline float row16_sum(float x) {
    x = dpp_add<0xB1>(x);    // quad_perm(1,0,3,2): ^1
    x = dpp_add<0x4E>(x);    // quad_perm(2,3,0,1): ^2
    x = dpp_add<0x124>(x);   // row_ror:4
    x = dpp_add<0x128>(x);   // row_ror:8
    return x;
}

// ---- dtype-generic load helpers ----
__device__ __attribute__((always_inline)) inline void ld8(const float* p, float* o) {
    f32x4 a = *(const f32x4*)p;
    f32x4 b = *(const f32x4*)(p + 4);
    o[0] = a[0]; o[1] = a[1]; o[2] = a[2]; o[3] = a[3];
    o[4] = b[0]; o[5] = b[1]; o[6] = b[2]; o[7] = b[3];
}
__device__ __attribute__((always_inline)) inline void ld8(const bf16_t* p, float* o) {
    bf16x8 v = *(const bf16x8*)p;
    #pragma unroll
    for (int e = 0; e < 8; ++e) o[e] = (float)v[e];
}
__device__ __attribute__((always_inline)) inline bf16x8 ld8b(const float* p) {
    f32x4 a = *(const f32x4*)p;
    f32x4 b = *(const f32x4*)(p + 4);
    bf16x8 v;
    #pragma unroll
    for (int e = 0; e < 4; ++e) { v[e] = (bf16_t)a[e]; v[e + 4] = (bf16_t)b[e]; }
    return v;
}
__device__ __attribute__((always_inline)) inline bf16x8 ld8b(const bf16_t* p) { return *(const bf16x8*)p; }
__device__ __attribute__((always_inline)) inline bf16x4 ld4b(const float* p) {
    f32x4 a = *(const f32x4*)p;
    bf16x4 v;
    #pragma unroll
    for (int e = 0; e < 4; ++e) v[e] = (bf16_t)a[e];
    return v;
}
__device__ __attribute__((always_inline)) inline bf16x4 ld4b(const bf16_t* p) { return *(const bf16x4*)p; }

// ---------------- Kernel 1: node linear layers ----------------
// grid (768, 4): row x matrix; block 128
template<typename T>
__device__ void node_body(float* x,
    const T* h_nodes, const T* Uw, const T* Ub, const T* Vw, const T* Vb,
    const T* Aw, const T* Ab, const T* Bw, const T* Bb, const T* Cb,
    float* ws)
{
    const int row = blockIdx.x, m = blockIdx.y, t = threadIdx.x;
    x[t] = (float)h_nodes[row * HD + t];
    __syncthreads();

    const T* Ws[4] = {Aw, Bw, Vw, Uw};
    float bias;
    if (m == 0)      bias = (float)Ab[t] + (float)Cb[t];
    else if (m == 1) bias = (float)Bb[t];
    else if (m == 2) bias = (float)Vb[t];
    else             bias = (float)Ub[t];

    float acc = bias;
    const T* W = Ws[m] + (size_t)t * HD;
    #pragma unroll
    for (int kk = 0; kk < 16; ++kk) {
        float w8[8];
        ld8(W + kk * 8, w8);
        #pragma unroll
        for (int e = 0; e < 8; ++e) acc = fmaf(x[kk * 8 + e], w8[e], acc);
    }
    ws[m * SZ + row * HD + t] = acc;
}

__global__ __launch_bounds__(128) void node_linear(
    const void* h_nodes, const void* Uw, const void* Ub, const void* Vw, const void* Vb,
    const void* Aw, const void* Ab, const void* Bw, const void* Bb, const void* Cb,
    float* __restrict__ ws)
{
    __shared__ __align__(16) float x[HD];
    if (read_flag(ws))
        node_body<float>(x, (const float*)h_nodes, (const float*)Uw, (const float*)Ub,
                         (const float*)Vw, (const float*)Vb, (const float*)Aw, (const float*)Ab,
                         (const float*)Bw, (const float*)Bb, (const float*)Cb, ws);
    else
        node_body<bf16_t>(x, (const bf16_t*)h_nodes, (const bf16_t*)Uw, (const bf16_t*)Ub,
                          (const bf16_t*)Vw, (const bf16_t*)Vb, (const bf16_t*)Aw, (const bf16_t*)Ab,
                          (const bf16_t*)Bw, (const bf16_t*)Bb, (const bf16_t*)Cb, ws);
}

// ---------------- Kernel 2: edge pipeline; one 16-j tile per wave; Cw in LDS ----------------
// grid (384, JC, 2); block 256 = 4 waves.
// D = Cw * E^T: lane holds j = jc*64 + w*16 + lr; h = ct*16 + (l>>4)*4 + r (in registers).
struct Smem {
    bf16_t sCw[128 * (CWPITCH / 2)];
    float sAhC[HD], sGe[HD], sBe[HD];
    float sAgg[4][HD];
};

template<typename T>
__device__ void edge_body(Smem& sm,
    const T* __restrict__ h_edges, const T* __restrict__ adj,
    const T* __restrict__ Cw, const T* __restrict__ ge, const T* __restrict__ be,
    const float* __restrict__ ws, float* __restrict__ wagg, float* __restrict__ out)
{
    const int i = blockIdx.x, jc = blockIdx.y, b = blockIdx.z;
    const int bi = b * NN + i;
    const int t = threadIdx.x;
    const int l = t & 63, w = t >> 6;
    const int lr = l & 15, lg = l >> 4;
    const int hbase = lg * 4;

    // ---- stage Cw into LDS (padded rows); 16 threads per row -> contiguous 256B reads ----
    {
        const int slot = t & 15;
        #pragma unroll
        for (int p = 0; p < 8; ++p) {
            const int row = p * 16 + (t >> 4);
            bf16x8 v = ld8b(&Cw[(size_t)row * HD + slot * 8]);
            *(bf16x8*)((char*)sm.sCw + row * CWPITCH + slot * 16) = v;
        }
    }
    if (t < HD) {
        sm.sAhC[t] = ws[0 * SZ + bi * HD + t];
        sm.sGe[t]  = (float)ge[t];
        sm.sBe[t]  = (float)be[t];
    }

    __syncthreads();   // drains only the staging; prefetch comes AFTER (no barrier-drain)

    const T* Ebase = h_edges + (size_t)bi * NN * HD;
    const int j = jc * 64 + w * 16 + lr;
    const T* Erow = &Ebase[(size_t)j * HD];

    // ---- prefetch: mask + residual + Bh/Vh; latency hides under the K-loop ----
    const float mk = (float)adj[(size_t)bi * NN + j];
    bf16x4 res[8];
    #pragma unroll
    for (int ct = 0; ct < 8; ++ct)
        res[ct] = ld4b(&Erow[ct * 16 + hbase]);

    const float* Bhrow = ws + 1 * SZ + ((size_t)b * NN + j) * HD;
    const float* Vhrow = ws + 2 * SZ + ((size_t)b * NN + j) * HD;
    f32x4 bhv[8], vhv[8];
    #pragma unroll
    for (int ct = 0; ct < 8; ++ct) {
        bhv[ct] = *(const f32x4*)&Bhrow[ct * 16 + hbase];
        vhv[ct] = *(const f32x4*)&Vhrow[ct * 16 + hbase];
    }

    // ---- K-loop: per ks, 8 ds_read_b128 (Bf) + 1 global A-frag, 8 MFMA ----
    f32x4 acc[8];
    #pragma unroll
    for (int ct = 0; ct < 8; ++ct) acc[ct] = (f32x4){0.f, 0.f, 0.f, 0.f};
    #pragma unroll
    for (int ks = 0; ks < 4; ++ks) {
        bf16x8 a = ld8b(&Erow[ks * 32 + lg * 8]);
        #pragma unroll
        for (int ct = 0; ct < 8; ++ct) {
            bf16x8 Bf = *(const bf16x8*)((const char*)sm.sCw +
                          (ct * 16 + lr) * CWPITCH + (((ks << 2) | lg)) * 16);
            acc[ct] = __builtin_amdgcn_mfma_f32_16x16x32_bf16(Bf, a, acc[ct], 0, 0, 0);
        }
    }

    // ---- inlined epilogue: e_upd = acc + AhC + Bh; LN over h; gate+agg; store ----
    float* Orow = out + SZ + ((size_t)bi * NN + j) * HD;

    float sum = 0.f, ssq = 0.f;
    #pragma unroll
    for (int ct = 0; ct < 8; ++ct) {
        f32x4 e = acc[ct];
        f32x4 av = *(const f32x4*)&sm.sAhC[ct * 16 + hbase];
        e = e + av + bhv[ct];
        acc[ct] = e;
        #pragma unroll
        for (int r = 0; r < 4; ++r) { sum += e[r]; ssq = fmaf(e[r], e[r], ssq); }
    }
    sum += __shfl_xor(sum, 16); ssq += __shfl_xor(ssq, 16);
    sum += __shfl_xor(sum, 32); ssq += __shfl_xor(ssq, 32);
    const float mean = sum * (1.f / HD);
    const float rstd = rsqrtf(ssq * (1.f / HD) - mean * mean + 1e-5f);

    f32x4 agg4[8];
    #pragma unroll
    for (int ct = 0; ct < 8; ++ct) {
        f32x4 ge4 = *(const f32x4*)&sm.sGe[ct * 16 + hbase];
        f32x4 be4 = *(const f32x4*)&sm.sBe[ct * 16 + hbase];
        f32x4 o;
        #pragma unroll
        for (int r = 0; r < 4; ++r) {
            const float ee = acc[ct][r];
            // sigmoid via single-instruction v_rcp (1 ulp) instead of IEEE divide sequence
            const float g = __builtin_amdgcn_rcpf(1.f + exp2f(ee * -1.44269504f));
            agg4[ct][r] = g * mk * vhv[ct][r];
            float a = (ee - mean) * rstd;
            a = fmaf(a, ge4[r], be4[r]);
            a = fmaxf(a, 0.f);
            o[r] = (float)res[ct][r] + a;
        }
        *(f32x4*)&Orow[ct * 16 + hbase] = o;
    }

    // ---- reduce agg over j-lanes (lr, 16-lane rows) via VALU DPP ----
    #pragma unroll
    for (int ct = 0; ct < 8; ++ct)
        #pragma unroll
        for (int r = 0; r < 4; ++r)
            agg4[ct][r] = row16_sum(agg4[ct][r]);
    if (lr == 0) {
        #pragma unroll
        for (int ct = 0; ct < 8; ++ct)
            *(f32x4*)&sm.sAgg[w][ct * 16 + hbase] = agg4[ct];
    }
    __syncthreads();

    // ---- per-block partial agg -> wagg ----
    if (t < HD) {
        float p = sm.sAgg[0][t] + sm.sAgg[1][t] + sm.sAgg[2][t] + sm.sAgg[3][t];
        wagg[((size_t)jc * ROWS + bi) * HD + t] = p;
    }
}

__global__ __launch_bounds__(256) void edge_kernel(
    const void* h_edges, const void* adj, const void* Cw,
    const void* ge, const void* be,
    float* __restrict__ ws, float* __restrict__ out)
{
    __shared__ Smem sm;
    float* wagg = ws + 4 * SZ;
    if (read_flag(ws))
        edge_body<float>(sm, (const float*)h_edges, (const float*)adj, (const float*)Cw,
                         (const float*)ge, (const float*)be, ws, wagg, out);
    else
        edge_body<bf16_t>(sm, (const bf16_t*)h_edges, (const bf16_t*)adj, (const bf16_t*)Cw,
                          (const bf16_t*)ge, (const bf16_t*)be, ws, wagg, out);
}

// ---------------- Kernel 3: node update ----------------
// grid 768; block 64 (one wave, 2 cols/lane)
template<typename T>
__device__ void node_upd_body(const T* h_nodes, const T* gh, const T* bh,
                              const float* ws, float* out)
{
    const int bi = blockIdx.x, t = threadIdx.x;
    float x0 = ws[3 * SZ + bi * HD + t];
    float x1 = ws[3 * SZ + bi * HD + t + 64];
    #pragma unroll
    for (int jc = 0; jc < JC; ++jc) {
        const float* p = ws + 4 * SZ + ((size_t)jc * ROWS + bi) * HD;
        x0 += p[t];
        x1 += p[t + 64];
    }
    float sum = x0 + x1;
    float ssq = x0 * x0 + x1 * x1;
    #pragma unroll
    for (int off = 1; off < 64; off <<= 1) {
        sum += __shfl_xor(sum, off);
        ssq += __shfl_xor(ssq, off);
    }
    const float mean = sum * (1.f / HD);
    const float rstd = rsqrtf(ssq * (1.f / HD) - mean * mean + 1e-5f);
    float a0 = fmaf((x0 - mean) * rstd, (float)gh[t],      (float)bh[t]);
    float a1 = fmaf((x1 - mean) * rstd, (float)gh[t + 64], (float)bh[t + 64]);
    a0 = fmaxf(a0, 0.f);
    a1 = fmaxf(a1, 0.f);
    out[bi * HD + t]      = (float)h_nodes[bi * HD + t]      + a0;
    out[bi * HD + t + 64] = (float)h_nodes[bi * HD + t + 64] + a1;
}

__global__ __launch_bounds__(64) void node_update(
    const void* h_nodes, const void* gh, const void* bh,
    const float* __restrict__ ws, float* __restrict__ out)
{
    if (read_flag(ws))
        node_upd_body<float>((const float*)h_nodes, (const float*)gh, (const float*)bh, ws, out);
    else
        node_upd_body<bf16_t>((const bf16_t*)h_nodes, (const bf16_t*)gh, (const bf16_t*)bh, ws, out);
}

extern "C" void kernel_launch(void* const* d_in, const int* in_sizes, int n_in,
                              void* d_out, int out_size, void* d_ws, size_t ws_size,
                              hipStream_t stream)
{
    float* ws = (float*)d_ws;
    float* out = (float*)d_out;

    detect_kernel<<<dim3(1), dim3(64), 0, stream>>>(d_in[0], ws);
    node_linear<<<dim3(ROWS, 4), dim3(128), 0, stream>>>(
        d_in[0], d_in[3], d_in[4], d_in[5], d_in[6], d_in[7], d_in[8],
        d_in[9], d_in[10], d_in[12], ws);
    edge_kernel<<<dim3(NN, JC, 2), dim3(256), 0, stream>>>(
        d_in[1], d_in[2], d_in[11], d_in[15], d_in[16], ws, out);
    node_update<<<dim3(ROWS), dim3(64), 0, stream>>>(
        d_in[0], d_in[13], d_in[14], ws, out);
}

// Round 19
// 139.823 us; speedup vs baseline: 1.1808x; 1.0049x over previous
//
#include <hip/hip_runtime.h>
#include <hip/hip_bf16.h>

typedef __bf16 bf16_t;
typedef __bf16 bf16x8 __attribute__((ext_vector_type(8)));
typedef __bf16 bf16x4 __attribute__((ext_vector_type(4)));
typedef float f32x4 __attribute__((ext_vector_type(4)));

#define HD 128
#define NN 384
#define ROWS 768           // B*N
#define SZ 98304           // ROWS*HD
#define JC 3               // j-chunks per (b,i): block covers 128 j (8 waves x 16 j)
#define CWPITCH 272        // bytes per sCw row: 256 + 16 pad
// ws layout: slot0 = AhC (f32), slot1 = Bh (bf16), slot2 = Vh (bf16), slot3 = Uh (f32),
// [4*SZ..7*SZ) = wagg f32 [JC][ROWS][HD]; flag at byte 7*SZ*4

// ---- runtime input-dtype detector: 1 if buffer holds f32, 0 if bf16 ----
__device__ inline int detect_f32(const void* p) {
    const unsigned short* u = (const unsigned short*)p;
    int bad = 0;
    #pragma unroll
    for (int k = 0; k < 128; ++k) {
        int e = (u[k] >> 7) & 0xFF;
        bad += (e < 110 || e > 135) ? 1 : 0;
    }
    return bad >= 16 ? 1 : 0;
}

__global__ __launch_bounds__(64) void detect_kernel(const void* p, float* ws) {
    if (threadIdx.x == 0)
        *(int*)((char*)ws + (size_t)7 * SZ * 4) = detect_f32(p);
}

__device__ inline int read_flag(const float* ws) {
    return *(const int*)((const char*)ws + (size_t)7 * SZ * 4);
}

// ---- DPP 16-lane (row) sum reduction: quad_perm ^1, ^2 then row_ror 4, 8 ----
template<int CTRL>
__device__ __attribute__((always_inline)) inline float dpp_add(float x) {
    int xi = __builtin_bit_cast(int, x);
    int yi = __builtin_amdgcn_update_dpp(0, xi, CTRL, 0xF, 0xF, true);
    return x + __builtin_bit_cast(float, yi);
}
__device__ __attribute__((always_inline)) inline float row16_sum(float x) {
    x = dpp_add<0xB1>(x);    // quad_perm(1,0,3,2): ^1
    x = dpp_add<0x4E>(x);    // quad_perm(2,3,0,1): ^2
    x = dpp_add<0x124>(x);   // row_ror:4
    x = dpp_add<0x128>(x);   // row_ror:8
    return x;
}

// ---- dtype-generic load helpers ----
__device__ __attribute__((always_inline)) inline void ld8(const float* p, float* o) {
    f32x4 a = *(const f32x4*)p;
    f32x4 b = *(const f32x4*)(p + 4);
    o[0] = a[0]; o[1] = a[1]; o[2] = a[2]; o[3] = a[3];
    o[4] = b[0]; o[5] = b[1]; o[6] = b[2]; o[7] = b[3];
}
__device__ __attribute__((always_inline)) inline void ld8(const bf16_t* p, float* o) {
    bf16x8 v = *(const bf16x8*)p;
    #pragma unroll
    for (int e = 0; e < 8; ++e) o[e] = (float)v[e];
}
__device__ __attribute__((always_inline)) inline bf16x8 ld8b(const float* p) {
    f32x4 a = *(const f32x4*)p;
    f32x4 b = *(const f32x4*)(p + 4);
    bf16x8 v;
    #pragma unroll
    for (int e = 0; e < 4; ++e) { v[e] = (bf16_t)a[e]; v[e + 4] = (bf16_t)b[e]; }
    return v;
}
__device__ __attribute__((always_inline)) inline bf16x8 ld8b(const bf16_t* p) { return *(const bf16x8*)p; }
__device__ __attribute__((always_inline)) inline bf16x4 ld4b(const float* p) {
    f32x4 a = *(const f32x4*)p;
    bf16x4 v;
    #pragma unroll
    for (int e = 0; e < 4; ++e) v[e] = (bf16_t)a[e];
    return v;
}
__device__ __attribute__((always_inline)) inline bf16x4 ld4b(const bf16_t* p) { return *(const bf16x4*)p; }

// ---------------- Kernel 1: node linear layers ----------------
// grid (768, 4): row x matrix; block 128.  Bh (m=1) and Vh (m=2) stored bf16.
template<typename T>
__device__ void node_body(float* x,
    const T* h_nodes, const T* Uw, const T* Ub, const T* Vw, const T* Vb,
    const T* Aw, const T* Ab, const T* Bw, const T* Bb, const T* Cb,
    float* ws)
{
    const int row = blockIdx.x, m = blockIdx.y, t = threadIdx.x;
    x[t] = (float)h_nodes[row * HD + t];
    __syncthreads();

    const T* Ws[4] = {Aw, Bw, Vw, Uw};
    float bias;
    if (m == 0)      bias = (float)Ab[t] + (float)Cb[t];
    else if (m == 1) bias = (float)Bb[t];
    else if (m == 2) bias = (float)Vb[t];
    else             bias = (float)Ub[t];

    float acc = bias;
    const T* W = Ws[m] + (size_t)t * HD;
    #pragma unroll
    for (int kk = 0; kk < 16; ++kk) {
        float w8[8];
        ld8(W + kk * 8, w8);
        #pragma unroll
        for (int e = 0; e < 8; ++e) acc = fmaf(x[kk * 8 + e], w8[e], acc);
    }
    if (m == 1 || m == 2)
        ((bf16_t*)(ws + (size_t)m * SZ))[row * HD + t] = (bf16_t)acc;
    else
        ws[(size_t)m * SZ + row * HD + t] = acc;
}

__global__ __launch_bounds__(128) void node_linear(
    const void* h_nodes, const void* Uw, const void* Ub, const void* Vw, const void* Vb,
    const void* Aw, const void* Ab, const void* Bw, const void* Bb, const void* Cb,
    float* __restrict__ ws)
{
    __shared__ __align__(16) float x[HD];
    if (read_flag(ws))
        node_body<float>(x, (const float*)h_nodes, (const float*)Uw, (const float*)Ub,
                         (const float*)Vw, (const float*)Vb, (const float*)Aw, (const float*)Ab,
                         (const float*)Bw, (const float*)Bb, (const float*)Cb, ws);
    else
        node_body<bf16_t>(x, (const bf16_t*)h_nodes, (const bf16_t*)Uw, (const bf16_t*)Ub,
                          (const bf16_t*)Vw, (const bf16_t*)Vb, (const bf16_t*)Aw, (const bf16_t*)Ab,
                          (const bf16_t*)Bw, (const bf16_t*)Bb, (const bf16_t*)Cb, ws);
}

// ---------------- Kernel 2: edge pipeline; one 16-j tile per wave; 8 waves/block ----------------
// grid (384, JC, 2); block 512 = 8 waves; Cw staged once per block (serves 128 j).
// D = Cw * E^T: lane holds j = jc*128 + w*16 + lr; h = ct*16 + (l>>4)*4 + r (in registers).
struct Smem {
    bf16_t sCw[128 * (CWPITCH / 2)];
    float sAhC[HD], sGe[HD], sBe[HD];
    float sAgg[8][HD];
};

template<typename T>
__device__ void edge_body(Smem& sm,
    const T* __restrict__ h_edges, const T* __restrict__ adj,
    const T* __restrict__ Cw, const T* __restrict__ ge, const T* __restrict__ be,
    const float* __restrict__ ws, float* __restrict__ wagg, float* __restrict__ out)
{
    const int i = blockIdx.x, jc = blockIdx.y, b = blockIdx.z;
    const int bi = b * NN + i;
    const int t = threadIdx.x;
    const int l = t & 63, w = t >> 6;
    const int lr = l & 15, lg = l >> 4;
    const int hbase = lg * 4;

    // ---- stage Cw into LDS (padded rows); 512 threads -> 4 rows each ----
    {
        const int slot = t & 15;
        #pragma unroll
        for (int p = 0; p < 4; ++p) {
            const int row = p * 32 + (t >> 4);
            bf16x8 v = ld8b(&Cw[(size_t)row * HD + slot * 8]);
            *(bf16x8*)((char*)sm.sCw + row * CWPITCH + slot * 16) = v;
        }
    }
    if (t < HD) {
        sm.sAhC[t] = ws[0 * SZ + bi * HD + t];
        sm.sGe[t]  = (float)ge[t];
        sm.sBe[t]  = (float)be[t];
    }

    __syncthreads();   // drains only the staging; prefetch comes AFTER (no barrier-drain)

    const T* Ebase = h_edges + (size_t)bi * NN * HD;
    const int j = jc * 128 + w * 16 + lr;
    const T* Erow = &Ebase[(size_t)j * HD];

    // ---- prefetch: mask + residual + Bh/Vh (bf16); latency hides under the K-loop ----
    const float mk = (float)adj[(size_t)bi * NN + j];
    bf16x4 res[8];
    #pragma unroll
    for (int ct = 0; ct < 8; ++ct)
        res[ct] = ld4b(&Erow[ct * 16 + hbase]);

    const bf16_t* Bhrow = (const bf16_t*)(ws + 1 * SZ) + ((size_t)b * NN + j) * HD;
    const bf16_t* Vhrow = (const bf16_t*)(ws + 2 * SZ) + ((size_t)b * NN + j) * HD;
    bf16x4 bhv[8], vhv[8];
    #pragma unroll
    for (int ct = 0; ct < 8; ++ct) {
        bhv[ct] = *(const bf16x4*)&Bhrow[ct * 16 + hbase];
        vhv[ct] = *(const bf16x4*)&Vhrow[ct * 16 + hbase];
    }

    // ---- K-loop: per ks, 8 ds_read_b128 (Bf) + 1 global A-frag, 8 MFMA ----
    f32x4 acc[8];
    #pragma unroll
    for (int ct = 0; ct < 8; ++ct) acc[ct] = (f32x4){0.f, 0.f, 0.f, 0.f};
    #pragma unroll
    for (int ks = 0; ks < 4; ++ks) {
        bf16x8 a = ld8b(&Erow[ks * 32 + lg * 8]);
        #pragma unroll
        for (int ct = 0; ct < 8; ++ct) {
            bf16x8 Bf = *(const bf16x8*)((const char*)sm.sCw +
                          (ct * 16 + lr) * CWPITCH + (((ks << 2) | lg)) * 16);
            acc[ct] = __builtin_amdgcn_mfma_f32_16x16x32_bf16(Bf, a, acc[ct], 0, 0, 0);
        }
    }

    // ---- inlined epilogue: e_upd = acc + AhC + Bh; LN over h; gate+agg; store ----
    float* Orow = out + SZ + ((size_t)bi * NN + j) * HD;

    float sum = 0.f, ssq = 0.f;
    #pragma unroll
    for (int ct = 0; ct < 8; ++ct) {
        f32x4 e = acc[ct];
        f32x4 av = *(const f32x4*)&sm.sAhC[ct * 16 + hbase];
        #pragma unroll
        for (int r = 0; r < 4; ++r) e[r] = e[r] + av[r] + (float)bhv[ct][r];
        acc[ct] = e;
        #pragma unroll
        for (int r = 0; r < 4; ++r) { sum += e[r]; ssq = fmaf(e[r], e[r], ssq); }
    }
    sum += __shfl_xor(sum, 16); ssq += __shfl_xor(ssq, 16);
    sum += __shfl_xor(sum, 32); ssq += __shfl_xor(ssq, 32);
    const float mean = sum * (1.f / HD);
    const float rstd = rsqrtf(ssq * (1.f / HD) - mean * mean + 1e-5f);

    f32x4 agg4[8];
    #pragma unroll
    for (int ct = 0; ct < 8; ++ct) {
        f32x4 ge4 = *(const f32x4*)&sm.sGe[ct * 16 + hbase];
        f32x4 be4 = *(const f32x4*)&sm.sBe[ct * 16 + hbase];
        f32x4 o;
        #pragma unroll
        for (int r = 0; r < 4; ++r) {
            const float ee = acc[ct][r];
            const float g = __builtin_amdgcn_rcpf(1.f + exp2f(ee * -1.44269504f));
            agg4[ct][r] = g * mk * (float)vhv[ct][r];
            float a = (ee - mean) * rstd;
            a = fmaf(a, ge4[r], be4[r]);
            a = fmaxf(a, 0.f);
            o[r] = (float)res[ct][r] + a;
        }
        *(f32x4*)&Orow[ct * 16 + hbase] = o;
    }

    // ---- reduce agg over j-lanes (lr, 16-lane rows) via VALU DPP ----
    #pragma unroll
    for (int ct = 0; ct < 8; ++ct)
        #pragma unroll
        for (int r = 0; r < 4; ++r)
            agg4[ct][r] = row16_sum(agg4[ct][r]);
    if (lr == 0) {
        #pragma unroll
        for (int ct = 0; ct < 8; ++ct)
            *(f32x4*)&sm.sAgg[w][ct * 16 + hbase] = agg4[ct];
    }
    __syncthreads();

    // ---- per-block partial agg -> wagg ----
    if (t < HD) {
        float p = sm.sAgg[0][t] + sm.sAgg[1][t] + sm.sAgg[2][t] + sm.sAgg[3][t]
                + sm.sAgg[4][t] + sm.sAgg[5][t] + sm.sAgg[6][t] + sm.sAgg[7][t];
        wagg[((size_t)jc * ROWS + bi) * HD + t] = p;
    }
}

__global__ __launch_bounds__(512, 2) void edge_kernel(
    const void* h_edges, const void* adj, const void* Cw,
    const void* ge, const void* be,
    float* __restrict__ ws, float* __restrict__ out)
{
    __shared__ Smem sm;
    float* wagg = ws + 4 * SZ;
    if (read_flag(ws))
        edge_body<float>(sm, (const float*)h_edges, (const float*)adj, (const float*)Cw,
                         (const float*)ge, (const float*)be, ws, wagg, out);
    else
        edge_body<bf16_t>(sm, (const bf16_t*)h_edges, (const bf16_t*)adj, (const bf16_t*)Cw,
                          (const bf16_t*)ge, (const bf16_t*)be, ws, wagg, out);
}

// ---------------- Kernel 3: node update ----------------
// grid 768; block 64 (one wave, 2 cols/lane)
template<typename T>
__device__ void node_upd_body(const T* h_nodes, const T* gh, const T* bh,
                              const float* ws, float* out)
{
    const int bi = blockIdx.x, t = threadIdx.x;
    float x0 = ws[3 * SZ + bi * HD + t];
    float x1 = ws[3 * SZ + bi * HD + t + 64];
    #pragma unroll
    for (int jc = 0; jc < JC; ++jc) {
        const float* p = ws + 4 * SZ + ((size_t)jc * ROWS + bi) * HD;
        x0 += p[t];
        x1 += p[t + 64];
    }
    float sum = x0 + x1;
    float ssq = x0 * x0 + x1 * x1;
    #pragma unroll
    for (int off = 1; off < 64; off <<= 1) {
        sum += __shfl_xor(sum, off);
        ssq += __shfl_xor(ssq, off);
    }
    const float mean = sum * (1.f / HD);
    const float rstd = rsqrtf(ssq * (1.f / HD) - mean * mean + 1e-5f);
    float a0 = fmaf((x0 - mean) * rstd, (float)gh[t],      (float)bh[t]);
    float a1 = fmaf((x1 - mean) * rstd, (float)gh[t + 64], (float)bh[t + 64]);
    a0 = fmaxf(a0, 0.f);
    a1 = fmaxf(a1, 0.f);
    out[bi * HD + t]      = (float)h_nodes[bi * HD + t]      + a0;
    out[bi * HD + t + 64] = (float)h_nodes[bi * HD + t + 64] + a1;
}

__global__ __launch_bounds__(64) void node_update(
    const void* h_nodes, const void* gh, const void* bh,
    const float* __restrict__ ws, float* __restrict__ out)
{
    if (read_flag(ws))
        node_upd_body<float>((const float*)h_nodes, (const float*)gh, (const float*)bh, ws, out);
    else
        node_upd_body<bf16_t>((const bf16_t*)h_nodes, (const bf16_t*)gh, (const bf16_t*)bh, ws, out);
}

extern "C" void kernel_launch(void* const* d_in, const int* in_sizes, int n_in,
                              void* d_out, int out_size, void* d_ws, size_t ws_size,
                              hipStream_t stream)
{
    float* ws = (float*)d_ws;
    float* out = (float*)d_out;

    detect_kernel<<<dim3(1), dim3(64), 0, stream>>>(d_in[0], ws);
    node_linear<<<dim3(ROWS, 4), dim3(128), 0, stream>>>(
        d_in[0], d_in[3], d_in[4], d_in[5], d_in[6], d_in[7], d_in[8],
        d_in[9], d_in[10], d_in[12], ws);
    edge_kernel<<<dim3(NN, JC, 2), dim3(512), 0, stream>>>(
        d_in[1], d_in[2], d_in[11], d_in[15], d_in[16], ws, out);
    node_update<<<dim3(ROWS), dim3(64), 0, stream>>>(
        d_in[0], d_in[13], d_in[14], ws, out);
}